// Round 18
// baseline (2557.850 us; speedup 1.0000x reference)
//
#include <hip/hip_runtime.h>
#include <hip/hip_bf16.h>

#define NB 8
#define NN 8192
#define NPOINT 2048
#define NSAMPLE 32
#define CIN 64
#define COUT 128

// ---------------------------------------------------------------------------
// Kernel 1: FPS — XLA:CPU contraction (verified round 16):
//   d = fma(dz,dz, fma(dx,dx, dy*dy)), f32, argmax first-index on ties.
// 1024 threads, 8 pts/thread. Inner loop is FLOAT-ONLY (min+max); the
// winning index is extracted post-loop by descending-k equality select
// (== first matching k = smallest idx). Cross-wave/block argmax via u64
// packed key (dist_bits<<32 | ~idx): max key == max dist, min index on
// exact ties — bit-identical semantics to rounds 16/17.
// Block stage: broadcast-group butterfly (all lanes load wkey[lane&15],
// 4 shfl_xor steps) instead of a serial 16-entry scan.
// ---------------------------------------------------------------------------
__global__ __launch_bounds__(1024) void fps_kernel(const float* __restrict__ xyz,
                                                   int* __restrict__ fps) {
  __shared__ float4 sp4[NN];                      // 128 KiB
  __shared__ unsigned long long wkey[2][16];

  const int b = blockIdx.x;
  const float* P = xyz + (size_t)b * NN * 3;
  const int t = threadIdx.x;

  float px[8], py[8], pz[8], dist[8];
#pragma unroll
  for (int k = 0; k < 8; ++k) {
    int i = t + k * 1024;
    float x = P[i * 3 + 0];
    float y = P[i * 3 + 1];
    float z = P[i * 3 + 2];
    px[k] = x; py[k] = y; pz[k] = z;
    sp4[i] = make_float4(x, y, z, 0.0f);
    dist[k] = 1e10f;
  }
  if (t == 0) fps[b * NPOINT + 0] = 0;
  __syncthreads();

  float qx = sp4[0].x, qy = sp4[0].y, qz = sp4[0].z;

  for (int it = 1; it < NPOINT; ++it) {
    // ---- distance update + float-only max tracking (8 VALU / point) ----
    float best = -1.0f;
#pragma unroll
    for (int k = 0; k < 8; ++k) {
      float dx = px[k] - qx, dy = py[k] - qy, dz = pz[k] - qz;
      float d = __fmaf_rn(dz, dz, __fmaf_rn(dx, dx, __fmul_rn(dy, dy)));
      float nd = fminf(dist[k], d);
      dist[k] = nd;
      best = fmaxf(best, nd);
    }
    // ---- post-loop index extraction: descending k => smallest matching k ----
    int ic = 0;
#pragma unroll
    for (int k = 7; k >= 0; --k) {
      ic = (dist[k] == best) ? (t + k * 1024) : ic;
    }
    unsigned long long key =
        ((unsigned long long)__float_as_uint(best) << 32) |
        (unsigned long long)(0xFFFFFFFFu - (unsigned)ic);
    // ---- wave butterfly: u64 max ----
#pragma unroll
    for (int off = 32; off > 0; off >>= 1) {
      unsigned long long ok = __shfl_xor(key, off);
      if (ok > key) key = ok;
    }
    if ((t & 63) == 0) wkey[it & 1][t >> 6] = key;
    __syncthreads();

    // ---- block stage: broadcast-group butterfly over the 16 wave keys ----
    unsigned long long g = wkey[it & 1][t & 15];
#pragma unroll
    for (int off = 1; off < 16; off <<= 1) {
      unsigned long long ok = __shfl_xor(g, off);
      if (ok > g) g = ok;
    }
    int gi = (int)(0xFFFFFFFFu - (unsigned)(g & 0xFFFFFFFFull));
    float4 q = sp4[gi];                           // uniform addr: broadcast
    qx = q.x; qy = q.y; qz = q.z;
    if (t == 0) fps[b * NPOINT + it] = gi;
  }
}

// ---------------------------------------------------------------------------
// Kernel 2: ball query — wave-parallel ballot compaction. A-form f32 d2;
// membership (double)d2 < 0.04000000000000001 (verified round-16 predicate).
// ---------------------------------------------------------------------------
__global__ __launch_bounds__(256) void ballq_kernel(const float* __restrict__ xyz,
                                                    const int* __restrict__ fps,
                                                    int* __restrict__ idx) {
  const int w = (int)((blockIdx.x * 256 + threadIdx.x) >> 6);
  const int lane = threadIdx.x & 63;
  const int b = w >> 11;
  const int m = w & 2047;
  const float* P = xyz + (size_t)b * NN * 3;
  const int ci = fps[b * NPOINT + m];
  const float cx = P[ci * 3 + 0], cy = P[ci * 3 + 1], cz = P[ci * 3 + 2];
  int* out = idx + (size_t)w * NSAMPLE;

  int cnt = 0;
  int first = -1;
  for (int s = 0; s < NN && cnt < NSAMPLE; s += 64) {
    int i = s + lane;
    float dx = P[i * 3 + 0] - cx;
    float dy = P[i * 3 + 1] - cy;
    float dz = P[i * 3 + 2] - cz;
    float d2 = __fadd_rn(__fadd_rn(__fmul_rn(dx, dx), __fmul_rn(dy, dy)),
                         __fmul_rn(dz, dz));
    bool inb = (double)d2 < 0.04000000000000001;
    unsigned long long mk = __ballot(inb);
    if (first < 0 && mk) first = s + (int)__builtin_ctzll(mk);
    int pos = cnt + __popcll(mk & ((1ull << lane) - 1ull));
    if (inb && pos < NSAMPLE) out[pos] = i;
    cnt += (int)__popcll(mk);
  }
  if (cnt < NSAMPLE) {
    if (lane >= cnt && lane < NSAMPLE) out[lane] = first;
  }
}

// ---------------------------------------------------------------------------
// Kernel 3: transpose feats [B][C][N] -> [B][N][C] for coalesced gathers.
// ---------------------------------------------------------------------------
__global__ __launch_bounds__(256) void transpose_kernel(
    const float* __restrict__ f, float* __restrict__ ft) {
  __shared__ float tile[64][65];
  const int b = blockIdx.y;
  const int n0 = blockIdx.x * 64;
  const int tx = threadIdx.x & 63;
  const int ty = threadIdx.x >> 6;
#pragma unroll
  for (int j = 0; j < 16; ++j) {
    int c = ty + j * 4;
    tile[c][tx] = f[((size_t)b * CIN + c) * NN + n0 + tx];
  }
  __syncthreads();
#pragma unroll
  for (int j = 0; j < 16; ++j) {
    int n = ty + j * 4;
    ft[((size_t)b * NN + n0 + n) * CIN + tx] = tile[tx][n];
  }
}

// ---------------------------------------------------------------------------
// Kernel 4: fused group + maxpool + 128x64 matvec on transposed feats.
// yt: [b][m][o].
// ---------------------------------------------------------------------------
__global__ __launch_bounds__(256) void fused_gpm_kernel(
    const float* __restrict__ ft, const int* __restrict__ idx,
    const float* __restrict__ W, float* __restrict__ yt) {
  __shared__ float sWt[64][129];
  __shared__ float sp[4][64];
  const int t = threadIdx.x;
#pragma unroll
  for (int j = 0; j < 32; ++j) {
    int q = j * 256 + t;
    sWt[q & 63][q >> 6] = W[q];
  }
  __syncthreads();

  const int w = t >> 6;
  const int lane = t & 63;
  const int gw = blockIdx.x * 4 + w;
  const int b = gw >> 11;
  const int* ip = idx + (size_t)gw * NSAMPLE;
  int myidx = (lane < NSAMPLE) ? ip[lane] : 0;
  const float* F = ft + (size_t)b * NN * CIN;
  float mx = -INFINITY;
#pragma unroll
  for (int s = 0; s < NSAMPLE; ++s) {
    int i = __shfl(myidx, s);
    mx = fmaxf(mx, F[(size_t)i * CIN + lane]);
  }
  sp[w][lane] = mx;
  __syncthreads();

  float acc0 = 0.0f, acc1 = 0.0f;
#pragma unroll
  for (int c = 0; c < 64; ++c) {
    float p = sp[w][c];
    acc0 += sWt[c][lane] * p;
    acc1 += sWt[c][lane + 64] * p;
  }
  float* yrow = yt + (size_t)gw * COUT;
  yrow[lane] = acc0;
  yrow[lane + 64] = acc1;
}

// ---------------------------------------------------------------------------
// Kernel 5a: stats stage A — contiguous-slab partial sums.
// ---------------------------------------------------------------------------
__global__ __launch_bounds__(256) void statsA_kernel(const float* __restrict__ yt,
                                                     float* __restrict__ part) {
  __shared__ float ls[128], ls2[128];
  const int bid = blockIdx.x;
  const int t = threadIdx.x;
  const int ch = t & 127;
  const int half = t >> 7;
  float s = 0.0f, s2 = 0.0f;
  const float* base = yt + (size_t)bid * 128 * 128;
  for (int r = half; r < 128; r += 2) {
    float v = base[r * 128 + ch];
    s += v;
    s2 += v * v;
  }
  if (half == 1) { ls[ch] = s; ls2[ch] = s2; }
  __syncthreads();
  if (half == 0) {
    s += ls[ch];
    s2 += ls2[ch];
    part[bid * 256 + ch] = s;
    part[bid * 256 + 128 + ch] = s2;
  }
}

// ---------------------------------------------------------------------------
// Kernel 5b: stats stage B — final reduce, scale/shift.
// ---------------------------------------------------------------------------
__global__ __launch_bounds__(128) void statsB_kernel(const float* __restrict__ part,
                                                     const float* __restrict__ gamma,
                                                     const float* __restrict__ beta,
                                                     float* __restrict__ ss) {
  const int o = threadIdx.x;
  float S = 0.0f, S2 = 0.0f;
  for (int bid = 0; bid < 128; ++bid) {
    S += part[bid * 256 + o];
    S2 += part[bid * 256 + 128 + o];
  }
  const float inv = 1.0f / (float)(NB * NPOINT);
  float mu = S * inv;
  float var = S2 * inv - mu * mu;
  if (var < 0.0f) var = 0.0f;
  float sc = gamma[o] / sqrtf(var + 1e-5f);
  ss[o] = sc;
  ss[128 + o] = beta[o] - mu * sc;
}

// ---------------------------------------------------------------------------
// Kernel 6: finalize. affine + leaky relu, transpose to out[b][o][m].
// ---------------------------------------------------------------------------
__global__ __launch_bounds__(256) void finalize_kernel(const float* __restrict__ yt,
                                                       const float* __restrict__ ss,
                                                       float* __restrict__ out) {
  __shared__ __align__(16) float sy[16][128];
  __shared__ float ssc[128], ssh[128];
  const int t = threadIdx.x;
  const int blk = blockIdx.x;
  const int b = blk >> 7;
  const int m0 = (blk & 127) * 16;
  if (t < 128) { ssc[t] = ss[t]; ssh[t] = ss[128 + t]; }
  const float* src = yt + ((size_t)(b * NPOINT + m0)) * 128;
  float4* s4 = (float4*)sy;
#pragma unroll
  for (int j = 0; j < 2; ++j) {
    int q = t + j * 256;
    s4[q] = ((const float4*)src)[q];
  }
  __syncthreads();
  const int o = t >> 1;
  const int half = t & 1;
  const float sc = ssc[o], sh = ssh[o];
  float r[8];
#pragma unroll
  for (int j = 0; j < 8; ++j) {
    float v = sy[half * 8 + j][o] * sc + sh;
    r[j] = (v >= 0.0f) ? v : __fmul_rn(0.2f, v);
  }
  float4* dst = (float4*)(out + ((size_t)(b * COUT + o)) * NPOINT + m0 + half * 8);
  dst[0] = make_float4(r[0], r[1], r[2], r[3]);
  dst[1] = make_float4(r[4], r[5], r[6], r[7]);
}

// ---------------------------------------------------------------------------
extern "C" void kernel_launch(void* const* d_in, const int* in_sizes, int n_in,
                              void* d_out, int out_size, void* d_ws, size_t ws_size,
                              hipStream_t stream) {
  const float* xyz = (const float*)d_in[0];
  const float* feats = (const float*)d_in[1];
  const float* W = (const float*)d_in[2];
  const float* gamma = (const float*)d_in[3];
  const float* beta = (const float*)d_in[4];
  float* out = (float*)d_out;

  char* ws = (char*)d_ws;
  int* fps = (int*)ws;                      // @0         64 KiB
  int* bidx = (int*)(ws + 65536);           // @64K       2 MiB
  float* ft = (float*)(ws + 2162688);       // @2.06M     16 MiB
  float* yt = (float*)(ws + 18939904);      // @18.06M    8 MiB
  float* part = (float*)(ws + 27328512);    // @26.06M    128 KiB
  float* ss = (float*)(ws + 27459584);      // @26.19M    1 KiB

  transpose_kernel<<<dim3(NN / 64, NB), 256, 0, stream>>>(feats, ft);
  fps_kernel<<<NB, 1024, 0, stream>>>(xyz, fps);
  ballq_kernel<<<(NB * NPOINT) / 4, 256, 0, stream>>>(xyz, fps, bidx);
  fused_gpm_kernel<<<(NB * NPOINT) / 4, 256, 0, stream>>>(ft, bidx, W, yt);
  statsA_kernel<<<128, 256, 0, stream>>>(yt, part);
  statsB_kernel<<<1, 128, 0, stream>>>(part, gamma, beta, ss);
  finalize_kernel<<<(NB * NPOINT) / 16, 256, 0, stream>>>(yt, ss, out);
}

// Round 19
// 2212.762 us; speedup vs baseline: 1.1560x; 1.1560x over previous
//
#include <hip/hip_runtime.h>
#include <hip/hip_bf16.h>

#define NB 8
#define NN 8192
#define NPOINT 2048
#define NSAMPLE 32
#define CIN 64
#define COUT 128

// ---------------------------------------------------------------------------
// Kernel 1: FPS — XLA:CPU contraction (verified round 16):
//   d = fma(dz,dz, fma(dx,dx, dy*dy)), f32, argmax first-index on ties.
// 512 threads (8 waves), 16 CONTIGUOUS pts/thread (thread t owns
// [16t,16t+16) so lane order == index order). Wave reduce: float butterfly
// max -> ballot(best==wbest) -> lowest lane -> its smallest matching k.
// Cross-wave: 8 u64 packed keys (dist_bits<<32 | ~idx), 3-step broadcast
// butterfly. Semantics bit-identical to rounds 16-18 (first-index ties).
// ---------------------------------------------------------------------------
__global__ __launch_bounds__(512) void fps_kernel(const float* __restrict__ xyz,
                                                  int* __restrict__ fps) {
  __shared__ float4 sp4[NN];                      // 128 KiB
  __shared__ unsigned long long wkey[2][8];

  const int b = blockIdx.x;
  const float* P = xyz + (size_t)b * NN * 3;
  const int t = threadIdx.x;
  const int lane = t & 63;
  const int wid = t >> 6;
  const int i0 = t * 16;

  float px[16], py[16], pz[16], dist[16];
#pragma unroll
  for (int k = 0; k < 16; ++k) {
    int i = i0 + k;
    float x = P[i * 3 + 0];
    float y = P[i * 3 + 1];
    float z = P[i * 3 + 2];
    px[k] = x; py[k] = y; pz[k] = z;
    sp4[i] = make_float4(x, y, z, 0.0f);
    dist[k] = 1e10f;
  }
  if (t == 0) fps[b * NPOINT + 0] = 0;
  __syncthreads();

  float qx = sp4[0].x, qy = sp4[0].y, qz = sp4[0].z;

  for (int it = 1; it < NPOINT; ++it) {
    // ---- distance update + float-only max (8 VALU / point) ----
    float best = -1.0f;
#pragma unroll
    for (int k = 0; k < 16; ++k) {
      float dx = px[k] - qx, dy = py[k] - qy, dz = pz[k] - qz;
      float d = __fmaf_rn(dz, dz, __fmaf_rn(dx, dx, __fmul_rn(dy, dy)));
      float nd = fminf(dist[k], d);
      dist[k] = nd;
      best = fmaxf(best, nd);
    }
    // ---- wave max: float butterfly (6 x shfl_xor+fmax) ----
    float wbest = best;
#pragma unroll
    for (int off = 32; off > 0; off >>= 1)
      wbest = fmaxf(wbest, __shfl_xor(wbest, off));
    // lowest lane holding the max; contiguous ownership => min lane = min idx
    unsigned long long mk = __ballot(best == wbest);
    int src = (int)__builtin_ctzll(mk);
    // this thread's smallest matching index (descending-k select)
    int ic = 0;
#pragma unroll
    for (int k = 15; k >= 0; --k)
      ic = (dist[k] == wbest) ? (i0 + k) : ic;
    int widx = __shfl(ic, src);

    if (lane == 0)
      wkey[it & 1][wid] =
          ((unsigned long long)__float_as_uint(wbest) << 32) |
          (unsigned long long)(0xFFFFFFFFu - (unsigned)widx);
    __syncthreads();

    // ---- block stage: broadcast-group butterfly over 8 wave keys ----
    unsigned long long g = wkey[it & 1][lane & 7];
#pragma unroll
    for (int off = 1; off < 8; off <<= 1) {
      unsigned long long o = __shfl_xor(g, off);
      if (o > g) g = o;
    }
    int gi = (int)(0xFFFFFFFFu - (unsigned)(g & 0xFFFFFFFFull));
    float4 q = sp4[gi];                           // uniform addr: broadcast
    qx = q.x; qy = q.y; qz = q.z;
    if (t == 0) fps[b * NPOINT + it] = gi;
  }
}

// ---------------------------------------------------------------------------
// Kernel 2: ball query — wave-parallel ballot compaction. A-form f32 d2;
// membership (double)d2 < 0.04000000000000001 (verified round-16 predicate).
// ---------------------------------------------------------------------------
__global__ __launch_bounds__(256) void ballq_kernel(const float* __restrict__ xyz,
                                                    const int* __restrict__ fps,
                                                    int* __restrict__ idx) {
  const int w = (int)((blockIdx.x * 256 + threadIdx.x) >> 6);
  const int lane = threadIdx.x & 63;
  const int b = w >> 11;
  const int m = w & 2047;
  const float* P = xyz + (size_t)b * NN * 3;
  const int ci = fps[b * NPOINT + m];
  const float cx = P[ci * 3 + 0], cy = P[ci * 3 + 1], cz = P[ci * 3 + 2];
  int* out = idx + (size_t)w * NSAMPLE;

  int cnt = 0;
  int first = -1;
  for (int s = 0; s < NN && cnt < NSAMPLE; s += 64) {
    int i = s + lane;
    float dx = P[i * 3 + 0] - cx;
    float dy = P[i * 3 + 1] - cy;
    float dz = P[i * 3 + 2] - cz;
    float d2 = __fadd_rn(__fadd_rn(__fmul_rn(dx, dx), __fmul_rn(dy, dy)),
                         __fmul_rn(dz, dz));
    bool inb = (double)d2 < 0.04000000000000001;
    unsigned long long mk = __ballot(inb);
    if (first < 0 && mk) first = s + (int)__builtin_ctzll(mk);
    int pos = cnt + __popcll(mk & ((1ull << lane) - 1ull));
    if (inb && pos < NSAMPLE) out[pos] = i;
    cnt += (int)__popcll(mk);
  }
  if (cnt < NSAMPLE) {
    if (lane >= cnt && lane < NSAMPLE) out[lane] = first;
  }
}

// ---------------------------------------------------------------------------
// Kernel 3: transpose feats [B][C][N] -> [B][N][C] for coalesced gathers.
// ---------------------------------------------------------------------------
__global__ __launch_bounds__(256) void transpose_kernel(
    const float* __restrict__ f, float* __restrict__ ft) {
  __shared__ float tile[64][65];
  const int b = blockIdx.y;
  const int n0 = blockIdx.x * 64;
  const int tx = threadIdx.x & 63;
  const int ty = threadIdx.x >> 6;
#pragma unroll
  for (int j = 0; j < 16; ++j) {
    int c = ty + j * 4;
    tile[c][tx] = f[((size_t)b * CIN + c) * NN + n0 + tx];
  }
  __syncthreads();
#pragma unroll
  for (int j = 0; j < 16; ++j) {
    int n = ty + j * 4;
    ft[((size_t)b * NN + n0 + n) * CIN + tx] = tile[tx][n];
  }
}

// ---------------------------------------------------------------------------
// Kernel 4: fused group + maxpool + 128x64 matvec on transposed feats.
// yt: [b][m][o].
// ---------------------------------------------------------------------------
__global__ __launch_bounds__(256) void fused_gpm_kernel(
    const float* __restrict__ ft, const int* __restrict__ idx,
    const float* __restrict__ W, float* __restrict__ yt) {
  __shared__ float sWt[64][129];
  __shared__ float sp[4][64];
  const int t = threadIdx.x;
#pragma unroll
  for (int j = 0; j < 32; ++j) {
    int q = j * 256 + t;
    sWt[q & 63][q >> 6] = W[q];
  }
  __syncthreads();

  const int w = t >> 6;
  const int lane = t & 63;
  const int gw = blockIdx.x * 4 + w;
  const int b = gw >> 11;
  const int* ip = idx + (size_t)gw * NSAMPLE;
  int myidx = (lane < NSAMPLE) ? ip[lane] : 0;
  const float* F = ft + (size_t)b * NN * CIN;
  float mx = -INFINITY;
#pragma unroll
  for (int s = 0; s < NSAMPLE; ++s) {
    int i = __shfl(myidx, s);
    mx = fmaxf(mx, F[(size_t)i * CIN + lane]);
  }
  sp[w][lane] = mx;
  __syncthreads();

  float acc0 = 0.0f, acc1 = 0.0f;
#pragma unroll
  for (int c = 0; c < 64; ++c) {
    float p = sp[w][c];
    acc0 += sWt[c][lane] * p;
    acc1 += sWt[c][lane + 64] * p;
  }
  float* yrow = yt + (size_t)gw * COUT;
  yrow[lane] = acc0;
  yrow[lane + 64] = acc1;
}

// ---------------------------------------------------------------------------
// Kernel 5a: stats stage A — contiguous-slab partial sums.
// ---------------------------------------------------------------------------
__global__ __launch_bounds__(256) void statsA_kernel(const float* __restrict__ yt,
                                                     float* __restrict__ part) {
  __shared__ float ls[128], ls2[128];
  const int bid = blockIdx.x;
  const int t = threadIdx.x;
  const int ch = t & 127;
  const int half = t >> 7;
  float s = 0.0f, s2 = 0.0f;
  const float* base = yt + (size_t)bid * 128 * 128;
  for (int r = half; r < 128; r += 2) {
    float v = base[r * 128 + ch];
    s += v;
    s2 += v * v;
  }
  if (half == 1) { ls[ch] = s; ls2[ch] = s2; }
  __syncthreads();
  if (half == 0) {
    s += ls[ch];
    s2 += ls2[ch];
    part[bid * 256 + ch] = s;
    part[bid * 256 + 128 + ch] = s2;
  }
}

// ---------------------------------------------------------------------------
// Kernel 5b: stats stage B — final reduce, scale/shift.
// ---------------------------------------------------------------------------
__global__ __launch_bounds__(128) void statsB_kernel(const float* __restrict__ part,
                                                     const float* __restrict__ gamma,
                                                     const float* __restrict__ beta,
                                                     float* __restrict__ ss) {
  const int o = threadIdx.x;
  float S = 0.0f, S2 = 0.0f;
  for (int bid = 0; bid < 128; ++bid) {
    S += part[bid * 256 + o];
    S2 += part[bid * 256 + 128 + o];
  }
  const float inv = 1.0f / (float)(NB * NPOINT);
  float mu = S * inv;
  float var = S2 * inv - mu * mu;
  if (var < 0.0f) var = 0.0f;
  float sc = gamma[o] / sqrtf(var + 1e-5f);
  ss[o] = sc;
  ss[128 + o] = beta[o] - mu * sc;
}

// ---------------------------------------------------------------------------
// Kernel 6: finalize. affine + leaky relu, transpose to out[b][o][m].
// ---------------------------------------------------------------------------
__global__ __launch_bounds__(256) void finalize_kernel(const float* __restrict__ yt,
                                                       const float* __restrict__ ss,
                                                       float* __restrict__ out) {
  __shared__ __align__(16) float sy[16][128];
  __shared__ float ssc[128], ssh[128];
  const int t = threadIdx.x;
  const int blk = blockIdx.x;
  const int b = blk >> 7;
  const int m0 = (blk & 127) * 16;
  if (t < 128) { ssc[t] = ss[t]; ssh[t] = ss[128 + t]; }
  const float* src = yt + ((size_t)(b * NPOINT + m0)) * 128;
  float4* s4 = (float4*)sy;
#pragma unroll
  for (int j = 0; j < 2; ++j) {
    int q = t + j * 256;
    s4[q] = ((const float4*)src)[q];
  }
  __syncthreads();
  const int o = t >> 1;
  const int half = t & 1;
  const float sc = ssc[o], sh = ssh[o];
  float r[8];
#pragma unroll
  for (int j = 0; j < 8; ++j) {
    float v = sy[half * 8 + j][o] * sc + sh;
    r[j] = (v >= 0.0f) ? v : __fmul_rn(0.2f, v);
  }
  float4* dst = (float4*)(out + ((size_t)(b * COUT + o)) * NPOINT + m0 + half * 8);
  dst[0] = make_float4(r[0], r[1], r[2], r[3]);
  dst[1] = make_float4(r[4], r[5], r[6], r[7]);
}

// ---------------------------------------------------------------------------
extern "C" void kernel_launch(void* const* d_in, const int* in_sizes, int n_in,
                              void* d_out, int out_size, void* d_ws, size_t ws_size,
                              hipStream_t stream) {
  const float* xyz = (const float*)d_in[0];
  const float* feats = (const float*)d_in[1];
  const float* W = (const float*)d_in[2];
  const float* gamma = (const float*)d_in[3];
  const float* beta = (const float*)d_in[4];
  float* out = (float*)d_out;

  char* ws = (char*)d_ws;
  int* fps = (int*)ws;                      // @0         64 KiB
  int* bidx = (int*)(ws + 65536);           // @64K       2 MiB
  float* ft = (float*)(ws + 2162688);       // @2.06M     16 MiB
  float* yt = (float*)(ws + 18939904);      // @18.06M    8 MiB
  float* part = (float*)(ws + 27328512);    // @26.06M    128 KiB
  float* ss = (float*)(ws + 27459584);      // @26.19M    1 KiB

  fps_kernel<<<NB, 512, 0, stream>>>(xyz, fps);
  transpose_kernel<<<dim3(NN / 64, NB), 256, 0, stream>>>(feats, ft);
  ballq_kernel<<<(NB * NPOINT) / 4, 256, 0, stream>>>(xyz, fps, bidx);
  fused_gpm_kernel<<<(NB * NPOINT) / 4, 256, 0, stream>>>(ft, bidx, W, yt);
  statsA_kernel<<<128, 256, 0, stream>>>(yt, part);
  statsB_kernel<<<1, 128, 0, stream>>>(part, gamma, beta, ss);
  finalize_kernel<<<(NB * NPOINT) / 16, 256, 0, stream>>>(yt, ss, out);
}

// Round 20
// 2137.249 us; speedup vs baseline: 1.1968x; 1.0353x over previous
//
#include <hip/hip_runtime.h>
#include <hip/hip_bf16.h>

#define NB 8
#define NN 8192
#define NPOINT 2048
#define NSAMPLE 32
#define CIN 64
#define COUT 128

// ---------------------------------------------------------------------------
// Kernel 1: FPS — XLA:CPU contraction (verified round 16):
//   d = fma(dz,dz, fma(dx,dx, dy*dy)), f32, argmax first-index on ties.
// 512 threads, 16 CONTIGUOUS pts/thread. Per-iter chain:
//   compute+tree-max -> f32 wave butterfly -> ballot/ctz -> shfl(ic)
//   -> lane0 ds_max_u64 (fire-and-forget) -> barrier
//   -> broadcast read slot -> extract gi -> broadcast read sp4[gi].
// u64 key = dist_bits<<32 | ~idx (max == max dist, min index on ties).
// 3-phase slot rotation: reset of slots[it+1 mod 3] is one barrier-epoch
// away from its last readers (2-phase would race in a 1-barrier loop).
// ---------------------------------------------------------------------------
__global__ __launch_bounds__(512) void fps_kernel(const float* __restrict__ xyz,
                                                  int* __restrict__ fps) {
  __shared__ float4 sp4[NN];                      // 128 KiB
  __shared__ unsigned long long slots[3];

  const int b = blockIdx.x;
  const float* P = xyz + (size_t)b * NN * 3;
  const int t = threadIdx.x;
  const int lane = t & 63;
  const int i0 = t * 16;

  float px[16], py[16], pz[16], dist[16];
#pragma unroll
  for (int k = 0; k < 16; ++k) {
    int i = i0 + k;
    float x = P[i * 3 + 0];
    float y = P[i * 3 + 1];
    float z = P[i * 3 + 2];
    px[k] = x; py[k] = y; pz[k] = z;
    sp4[i] = make_float4(x, y, z, 0.0f);
    dist[k] = 1e10f;
  }
  if (t == 0) {
    fps[b * NPOINT + 0] = 0;
    slots[0] = 0ull; slots[1] = 0ull; slots[2] = 0ull;
  }
  __syncthreads();

  float qx = sp4[0].x, qy = sp4[0].y, qz = sp4[0].z;

  int cur = 1;  // phase = it % 3
  for (int it = 1; it < NPOINT; ++it) {
    // ---- distance update (8 VALU/point) ----
#pragma unroll
    for (int k = 0; k < 16; ++k) {
      float dx = px[k] - qx, dy = py[k] - qy, dz = pz[k] - qz;
      float d = __fmaf_rn(dz, dz, __fmaf_rn(dx, dx, __fmul_rn(dy, dy)));
      dist[k] = fminf(dist[k], d);
    }
    // ---- tree max (depth 4) ----
    float m0 = fmaxf(dist[0], dist[1]),  m1 = fmaxf(dist[2], dist[3]);
    float m2 = fmaxf(dist[4], dist[5]),  m3 = fmaxf(dist[6], dist[7]);
    float m4 = fmaxf(dist[8], dist[9]),  m5 = fmaxf(dist[10], dist[11]);
    float m6 = fmaxf(dist[12], dist[13]), m7 = fmaxf(dist[14], dist[15]);
    m0 = fmaxf(m0, m1); m2 = fmaxf(m2, m3); m4 = fmaxf(m4, m5); m6 = fmaxf(m6, m7);
    m0 = fmaxf(m0, m2); m4 = fmaxf(m4, m6);
    float best = fmaxf(m0, m4);
    // ---- off-chain: smallest k with dist[k]==best (runs during butterfly) ----
    int ic = 0;
#pragma unroll
    for (int k = 15; k >= 0; --k)
      ic = (dist[k] == best) ? (i0 + k) : ic;
    // ---- wave butterfly: f32 max ----
    float wbest = best;
#pragma unroll
    for (int off = 32; off > 0; off >>= 1)
      wbest = fmaxf(wbest, __shfl_xor(wbest, off));
    // lowest lane with the max (contiguous ownership => min lane = min idx)
    unsigned long long mk = __ballot(best == wbest);
    int src = (int)__builtin_ctzll(mk);
    int widx = __shfl(ic, src);

    if (lane == 0) {
      unsigned long long key =
          ((unsigned long long)__float_as_uint(wbest) << 32) |
          (unsigned long long)(0xFFFFFFFFu - (unsigned)widx);
      atomicMax(&slots[cur], key);               // ds_max_u64, no return
    }
    int nxt = (cur == 2) ? 0 : cur + 1;
    if (t == 256) slots[nxt] = 0ull;             // epoch-safe reset (mod-3)
    __syncthreads();

    unsigned long long g = slots[cur];           // uniform addr: broadcast
    int gi = (int)(0xFFFFFFFFu - (unsigned)(g & 0xFFFFFFFFull));
    float4 q = sp4[gi];                          // uniform addr: broadcast
    qx = q.x; qy = q.y; qz = q.z;
    if (t == 0) fps[b * NPOINT + it] = gi;
    cur = nxt;
  }
}

// ---------------------------------------------------------------------------
// Kernel 2: ball query — wave-parallel ballot compaction. A-form f32 d2;
// membership (double)d2 < 0.04000000000000001 (verified round-16 predicate).
// ---------------------------------------------------------------------------
__global__ __launch_bounds__(256) void ballq_kernel(const float* __restrict__ xyz,
                                                    const int* __restrict__ fps,
                                                    int* __restrict__ idx) {
  const int w = (int)((blockIdx.x * 256 + threadIdx.x) >> 6);
  const int lane = threadIdx.x & 63;
  const int b = w >> 11;
  const int m = w & 2047;
  const float* P = xyz + (size_t)b * NN * 3;
  const int ci = fps[b * NPOINT + m];
  const float cx = P[ci * 3 + 0], cy = P[ci * 3 + 1], cz = P[ci * 3 + 2];
  int* out = idx + (size_t)w * NSAMPLE;

  int cnt = 0;
  int first = -1;
  for (int s = 0; s < NN && cnt < NSAMPLE; s += 64) {
    int i = s + lane;
    float dx = P[i * 3 + 0] - cx;
    float dy = P[i * 3 + 1] - cy;
    float dz = P[i * 3 + 2] - cz;
    float d2 = __fadd_rn(__fadd_rn(__fmul_rn(dx, dx), __fmul_rn(dy, dy)),
                         __fmul_rn(dz, dz));
    bool inb = (double)d2 < 0.04000000000000001;
    unsigned long long mk = __ballot(inb);
    if (first < 0 && mk) first = s + (int)__builtin_ctzll(mk);
    int pos = cnt + __popcll(mk & ((1ull << lane) - 1ull));
    if (inb && pos < NSAMPLE) out[pos] = i;
    cnt += (int)__popcll(mk);
  }
  if (cnt < NSAMPLE) {
    if (lane >= cnt && lane < NSAMPLE) out[lane] = first;
  }
}

// ---------------------------------------------------------------------------
// Kernel 3: transpose feats [B][C][N] -> [B][N][C] for coalesced gathers.
// ---------------------------------------------------------------------------
__global__ __launch_bounds__(256) void transpose_kernel(
    const float* __restrict__ f, float* __restrict__ ft) {
  __shared__ float tile[64][65];
  const int b = blockIdx.y;
  const int n0 = blockIdx.x * 64;
  const int tx = threadIdx.x & 63;
  const int ty = threadIdx.x >> 6;
#pragma unroll
  for (int j = 0; j < 16; ++j) {
    int c = ty + j * 4;
    tile[c][tx] = f[((size_t)b * CIN + c) * NN + n0 + tx];
  }
  __syncthreads();
#pragma unroll
  for (int j = 0; j < 16; ++j) {
    int n = ty + j * 4;
    ft[((size_t)b * NN + n0 + n) * CIN + tx] = tile[tx][n];
  }
}

// ---------------------------------------------------------------------------
// Kernel 4: fused group + maxpool + 128x64 matvec on transposed feats.
// yt: [b][m][o].
// ---------------------------------------------------------------------------
__global__ __launch_bounds__(256) void fused_gpm_kernel(
    const float* __restrict__ ft, const int* __restrict__ idx,
    const float* __restrict__ W, float* __restrict__ yt) {
  __shared__ float sWt[64][129];
  __shared__ float sp[4][64];
  const int t = threadIdx.x;
#pragma unroll
  for (int j = 0; j < 32; ++j) {
    int q = j * 256 + t;
    sWt[q & 63][q >> 6] = W[q];
  }
  __syncthreads();

  const int w = t >> 6;
  const int lane = t & 63;
  const int gw = blockIdx.x * 4 + w;
  const int b = gw >> 11;
  const int* ip = idx + (size_t)gw * NSAMPLE;
  int myidx = (lane < NSAMPLE) ? ip[lane] : 0;
  const float* F = ft + (size_t)b * NN * CIN;
  float mx = -INFINITY;
#pragma unroll
  for (int s = 0; s < NSAMPLE; ++s) {
    int i = __shfl(myidx, s);
    mx = fmaxf(mx, F[(size_t)i * CIN + lane]);
  }
  sp[w][lane] = mx;
  __syncthreads();

  float acc0 = 0.0f, acc1 = 0.0f;
#pragma unroll
  for (int c = 0; c < 64; ++c) {
    float p = sp[w][c];
    acc0 += sWt[c][lane] * p;
    acc1 += sWt[c][lane + 64] * p;
  }
  float* yrow = yt + (size_t)gw * COUT;
  yrow[lane] = acc0;
  yrow[lane + 64] = acc1;
}

// ---------------------------------------------------------------------------
// Kernel 5a: stats stage A — contiguous-slab partial sums.
// ---------------------------------------------------------------------------
__global__ __launch_bounds__(256) void statsA_kernel(const float* __restrict__ yt,
                                                     float* __restrict__ part) {
  __shared__ float ls[128], ls2[128];
  const int bid = blockIdx.x;
  const int t = threadIdx.x;
  const int ch = t & 127;
  const int half = t >> 7;
  float s = 0.0f, s2 = 0.0f;
  const float* base = yt + (size_t)bid * 128 * 128;
  for (int r = half; r < 128; r += 2) {
    float v = base[r * 128 + ch];
    s += v;
    s2 += v * v;
  }
  if (half == 1) { ls[ch] = s; ls2[ch] = s2; }
  __syncthreads();
  if (half == 0) {
    s += ls[ch];
    s2 += ls2[ch];
    part[bid * 256 + ch] = s;
    part[bid * 256 + 128 + ch] = s2;
  }
}

// ---------------------------------------------------------------------------
// Kernel 5b: stats stage B — final reduce, scale/shift.
// ---------------------------------------------------------------------------
__global__ __launch_bounds__(128) void statsB_kernel(const float* __restrict__ part,
                                                     const float* __restrict__ gamma,
                                                     const float* __restrict__ beta,
                                                     float* __restrict__ ss) {
  const int o = threadIdx.x;
  float S = 0.0f, S2 = 0.0f;
  for (int bid = 0; bid < 128; ++bid) {
    S += part[bid * 256 + o];
    S2 += part[bid * 256 + 128 + o];
  }
  const float inv = 1.0f / (float)(NB * NPOINT);
  float mu = S * inv;
  float var = S2 * inv - mu * mu;
  if (var < 0.0f) var = 0.0f;
  float sc = gamma[o] / sqrtf(var + 1e-5f);
  ss[o] = sc;
  ss[128 + o] = beta[o] - mu * sc;
}

// ---------------------------------------------------------------------------
// Kernel 6: finalize. affine + leaky relu, transpose to out[b][o][m].
// ---------------------------------------------------------------------------
__global__ __launch_bounds__(256) void finalize_kernel(const float* __restrict__ yt,
                                                       const float* __restrict__ ss,
                                                       float* __restrict__ out) {
  __shared__ __align__(16) float sy[16][128];
  __shared__ float ssc[128], ssh[128];
  const int t = threadIdx.x;
  const int blk = blockIdx.x;
  const int b = blk >> 7;
  const int m0 = (blk & 127) * 16;
  if (t < 128) { ssc[t] = ss[t]; ssh[t] = ss[128 + t]; }
  const float* src = yt + ((size_t)(b * NPOINT + m0)) * 128;
  float4* s4 = (float4*)sy;
#pragma unroll
  for (int j = 0; j < 2; ++j) {
    int q = t + j * 256;
    s4[q] = ((const float4*)src)[q];
  }
  __syncthreads();
  const int o = t >> 1;
  const int half = t & 1;
  const float sc = ssc[o], sh = ssh[o];
  float r[8];
#pragma unroll
  for (int j = 0; j < 8; ++j) {
    float v = sy[half * 8 + j][o] * sc + sh;
    r[j] = (v >= 0.0f) ? v : __fmul_rn(0.2f, v);
  }
  float4* dst = (float4*)(out + ((size_t)(b * COUT + o)) * NPOINT + m0 + half * 8);
  dst[0] = make_float4(r[0], r[1], r[2], r[3]);
  dst[1] = make_float4(r[4], r[5], r[6], r[7]);
}

// ---------------------------------------------------------------------------
extern "C" void kernel_launch(void* const* d_in, const int* in_sizes, int n_in,
                              void* d_out, int out_size, void* d_ws, size_t ws_size,
                              hipStream_t stream) {
  const float* xyz = (const float*)d_in[0];
  const float* feats = (const float*)d_in[1];
  const float* W = (const float*)d_in[2];
  const float* gamma = (const float*)d_in[3];
  const float* beta = (const float*)d_in[4];
  float* out = (float*)d_out;

  char* ws = (char*)d_ws;
  int* fps = (int*)ws;                      // @0         64 KiB
  int* bidx = (int*)(ws + 65536);           // @64K       2 MiB
  float* ft = (float*)(ws + 2162688);       // @2.06M     16 MiB
  float* yt = (float*)(ws + 18939904);      // @18.06M    8 MiB
  float* part = (float*)(ws + 27328512);    // @26.06M    128 KiB
  float* ss = (float*)(ws + 27459584);      // @26.19M    1 KiB

  fps_kernel<<<NB, 512, 0, stream>>>(xyz, fps);
  transpose_kernel<<<dim3(NN / 64, NB), 256, 0, stream>>>(feats, ft);
  ballq_kernel<<<(NB * NPOINT) / 4, 256, 0, stream>>>(xyz, fps, bidx);
  fused_gpm_kernel<<<(NB * NPOINT) / 4, 256, 0, stream>>>(ft, bidx, W, yt);
  statsA_kernel<<<128, 256, 0, stream>>>(yt, part);
  statsB_kernel<<<1, 128, 0, stream>>>(part, gamma, beta, ss);
  finalize_kernel<<<(NB * NPOINT) / 16, 256, 0, stream>>>(yt, ss, out);
}